// Round 2
// baseline (256.268 us; speedup 1.0000x reference)
//
#include <hip/hip_runtime.h>

#define LSEQ 200
#define KCAP 4
#define NVOC 100000

__device__ __forceinline__ void fma4(float4& a, float s, const float4& v) {
    a.x = fmaf(s, v.x, a.x); a.y = fmaf(s, v.y, a.y);
    a.z = fmaf(s, v.z, a.z); a.w = fmaf(s, v.w, a.w);
}

// ---------------------------------------------------------------------------
// Kernel 1: P = (E with row 0 zeroed) @ S.  lane = vocab row; E-row chunks in
// registers; S rows via b128 LDS broadcasts (cheap); 64 fp32 accumulators.
// VALU-bound ~5 us + 51 MB stream.
// ---------------------------------------------------------------------------
__global__ __launch_bounds__(256) void precompute_P(
    const float* __restrict__ E, const float* __restrict__ S,
    float* __restrict__ P)
{
    __shared__ __align__(16) float4 Sl4[1024];     // S[e][4j..4j+3] = Sl4[e*16+j]
    const int tid = threadIdx.x;
    #pragma unroll
    for (int t = tid; t < 1024; t += 256) Sl4[t] = ((const float4*)S)[t];
    __syncthreads();

    const int v = blockIdx.x * 256 + tid;
    const bool ok = (v < NVOC);
    const float4* __restrict__ Er = (const float4*)E + (size_t)(ok ? v : 0) * 16;

    float4 acc[16];
    #pragma unroll
    for (int j = 0; j < 16; j++) acc[j] = make_float4(0.f, 0.f, 0.f, 0.f);

    #pragma unroll 1
    for (int ec = 0; ec < 16; ec += 2) {           // 8 chunks of 8 e's
        float4 ea = Er[ec], eb = Er[ec + 1];
        float ev[8] = {ea.x, ea.y, ea.z, ea.w, eb.x, eb.y, eb.z, eb.w};
        #pragma unroll
        for (int e = 0; e < 8; e++) {
            const float4* Srow = Sl4 + (ec * 4 + e) * 16;
            #pragma unroll
            for (int j = 0; j < 16; j++) fma4(acc[j], ev[e], Srow[j]);  // b128 broadcast
        }
    }
    if (ok) {
        float4* Pr = (float4*)P + (size_t)v * 16;
        if (v == 0) {
            #pragma unroll
            for (int j = 0; j < 16; j++) acc[j] = make_float4(0.f, 0.f, 0.f, 0.f);
        }
        #pragma unroll
        for (int j = 0; j < 16; j++) Pr[j] = acc[j];
    }
}

// ---------------------------------------------------------------------------
// Kernel 2: one batch row per block. float4 everywhere; hisP rows stride-17
// float4 (conflict-free b128 spread at the 8-cycle floor).
// ---------------------------------------------------------------------------
__global__ __launch_bounds__(256, 2) void mind_row(
    const int*   __restrict__ his, const float* __restrict__ P,
    const float* __restrict__ B0,  const float* __restrict__ W1,
    const float* __restrict__ b1,  const float* __restrict__ W2,
    const float* __restrict__ b2,  float* __restrict__ out)
{
    __shared__ __align__(16) float4 hisP4[LSEQ * 17];   // 54400 B; row l at [l*17+r]
    __shared__ __align__(16) float  W4[LSEQ * 4];       // W4[l*4+k]
    __shared__ __align__(16) float  Bm[KCAP * LSEQ];
    __shared__ __align__(16) float  caps4[64 * 4];      // caps4[d*4+k]
    __shared__ __align__(16) float4 capsT4[KCAP * 16];  // capsT4[k*16+j] = caps[k][4j..4j+3]
    __shared__ __align__(16) float4 part4[16 * 17];     // [(w*4+k)*17 + r], 1088 floats
    __shared__ float bigneg[LSEQ];
    __shared__ int   idxs[LSEQ];

    const int b = blockIdx.x, tid = threadIdx.x;
    const int lane = tid & 63, wv = tid >> 6;
    const int q = lane >> 4, r = lane & 15;

    for (int l = tid; l < LSEQ; l += 256) {
        int id = his[b * LSEQ + l];
        idxs[l]   = id;
        bigneg[l] = (id != 0) ? 0.f : -1e30f;
    }
    for (int t = tid; t < KCAP * LSEQ; t += 256) Bm[t] = B0[t];
    __syncthreads();

    // Gather: wave wv covers l in [wv*50, wv*50+50); lane (q,r): l = base+4i+q,
    // d-chunk = r. 13 b128 global loads + 13 b128 LDS stores per thread.
    float4 hp4[13];
    const float4* P4 = (const float4*)P;
    #pragma unroll
    for (int i = 0; i < 13; i++) {
        int  l     = wv * 50 + i * 4 + q;
        bool valid = (i < 12) || (q < 2);              // 12*4+2 = 50
        int  lc    = valid ? l : 0;
        float4 vv  = P4[(size_t)idxs[lc] * 16 + r];
        if (!valid) vv = make_float4(0.f, 0.f, 0.f, 0.f);
        hp4[i] = vv;
        if (valid) hisP4[l * 17 + r] = vv;             // bank group (l+r)%8: uniform
    }
    __syncthreads();

    for (int rr = 0; rr < 3; rr++) {
        // A: masked softmax over l; capsule k = wv (one wave per capsule)
        {
            const float* Bk = Bm + wv * LSEQ;
            float x0 = Bk[lane]       + bigneg[lane];
            float x1 = Bk[lane + 64]  + bigneg[lane + 64];
            float x2 = Bk[lane + 128] + bigneg[lane + 128];
            float x3 = (lane < 8) ? (Bk[lane + 192] + bigneg[lane + 192]) : -3.0e38f;
            float m = fmaxf(fmaxf(x0, x1), fmaxf(x2, x3));
            #pragma unroll
            for (int off = 32; off; off >>= 1) m = fmaxf(m, __shfl_xor(m, off, 64));
            float e0 = __expf(x0 - m), e1 = __expf(x1 - m), e2 = __expf(x2 - m);
            float e3 = (lane < 8) ? __expf(x3 - m) : 0.f;
            float s = e0 + e1 + e2 + e3;
            #pragma unroll
            for (int off = 32; off; off >>= 1) s += __shfl_xor(s, off, 64);
            float inv = 1.f / s;
            W4[lane * 4 + wv]         = e0 * inv;
            W4[(lane + 64) * 4 + wv]  = e1 * inv;
            W4[(lane + 128) * 4 + wv] = e2 * inv;
            if (lane < 8) W4[(lane + 192) * 4 + wv] = e3 * inv;
        }
        __syncthreads();

        // B: caps partials from registers; only W4 b128 broadcasts touch LDS.
        {
            float4 a0 = make_float4(0,0,0,0), a1 = a0, a2 = a0, a3 = a0;
            #pragma unroll
            for (int i = 0; i < 13; i++) {
                int l  = wv * 50 + i * 4 + q;
                int lc = (l < LSEQ - 1) ? l : (LSEQ - 1);
                float4 w = *(const float4*)(W4 + lc * 4);   // 4-address b128, cheap
                fma4(a0, w.x, hp4[i]); fma4(a1, w.y, hp4[i]);
                fma4(a2, w.z, hp4[i]); fma4(a3, w.w, hp4[i]);
            }
            // reduce over q (lanes +-16, +-32)
            #pragma unroll
            for (int off = 16; off <= 32; off <<= 1) {
                a0.x += __shfl_xor(a0.x, off, 64); a0.y += __shfl_xor(a0.y, off, 64);
                a0.z += __shfl_xor(a0.z, off, 64); a0.w += __shfl_xor(a0.w, off, 64);
                a1.x += __shfl_xor(a1.x, off, 64); a1.y += __shfl_xor(a1.y, off, 64);
                a1.z += __shfl_xor(a1.z, off, 64); a1.w += __shfl_xor(a1.w, off, 64);
                a2.x += __shfl_xor(a2.x, off, 64); a2.y += __shfl_xor(a2.y, off, 64);
                a2.z += __shfl_xor(a2.z, off, 64); a2.w += __shfl_xor(a2.w, off, 64);
                a3.x += __shfl_xor(a3.x, off, 64); a3.y += __shfl_xor(a3.y, off, 64);
                a3.z += __shfl_xor(a3.z, off, 64); a3.w += __shfl_xor(a3.w, off, 64);
            }
            if (q == 0) {
                part4[(wv * 4 + 0) * 17 + r] = a0;
                part4[(wv * 4 + 1) * 17 + r] = a1;
                part4[(wv * 4 + 2) * 17 + r] = a2;
                part4[(wv * 4 + 3) * 17 + r] = a3;
            }
        }
        __syncthreads();

        // C: reduce wave partials + squash; thread = (k = wv, d = lane)
        {
            const float* pf = (const float*)part4;
            float c = pf[(0 * 4 + wv) * 68 + lane] + pf[(1 * 4 + wv) * 68 + lane]
                    + pf[(2 * 4 + wv) * 68 + lane] + pf[(3 * 4 + wv) * 68 + lane];
            float n2 = c * c;
            #pragma unroll
            for (int off = 32; off; off >>= 1) n2 += __shfl_xor(n2, off, 64);
            float n  = sqrtf(n2);
            float sc = n2 / ((1.f + n2) * n + 1e-9f);
            c *= sc;
            caps4[lane * 4 + wv]          = c;
            ((float*)capsT4)[wv * 64 + lane] = c;
        }
        __syncthreads();

        if (rr < 2) {
            // D: B[k][l] += caps[k].hisP[l]; thread per l; b128 reads at floor.
            if (tid < LSEQ) {
                const int l = tid;
                float s0 = 0, s1 = 0, s2 = 0, s3 = 0;
                #pragma unroll
                for (int j = 0; j < 16; j++) {
                    float4 h  = hisP4[l * 17 + j];
                    float4 c0 = capsT4[j],      c1 = capsT4[16 + j];
                    float4 c2 = capsT4[32 + j], c3 = capsT4[48 + j];
                    s0 = fmaf(h.x, c0.x, fmaf(h.y, c0.y, fmaf(h.z, c0.z, fmaf(h.w, c0.w, s0))));
                    s1 = fmaf(h.x, c1.x, fmaf(h.y, c1.y, fmaf(h.z, c1.z, fmaf(h.w, c1.w, s1))));
                    s2 = fmaf(h.x, c2.x, fmaf(h.y, c2.y, fmaf(h.z, c2.z, fmaf(h.w, c2.w, s2))));
                    s3 = fmaf(h.x, c3.x, fmaf(h.y, c3.y, fmaf(h.z, c3.z, fmaf(h.w, c3.w, s3))));
                }
                Bm[l]       += s0;
                Bm[200 + l] += s1;
                Bm[400 + l] += s2;
                Bm[600 + l] += s3;
            }
            __syncthreads();
        }
    }

    // MLP. hisP4 dead -> overlay h as float4 per f.
    float4* h44 = (float4*)hisP4;
    {
        const int f = tid;
        float h0 = 0, h1 = 0, h2 = 0, h3 = 0;
        #pragma unroll 8
        for (int d = 0; d < 64; d++) {
            float  w = W1[d * 256 + f];                       // coalesced, L2-hot
            float4 c = *(const float4*)(caps4 + d * 4);       // b128 broadcast
            h0 = fmaf(c.x, w, h0); h1 = fmaf(c.y, w, h1);
            h2 = fmaf(c.z, w, h2); h3 = fmaf(c.w, w, h3);
        }
        float bb = b1[f];
        h44[f] = make_float4(fmaxf(h0 + bb, 0.f), fmaxf(h1 + bb, 0.f),
                             fmaxf(h2 + bb, 0.f), fmaxf(h3 + bb, 0.f));
    }
    __syncthreads();
    float* partf = (float*)part4;                             // 1024 of 1088 floats
    {
        float o0 = 0, o1 = 0, o2 = 0, o3 = 0;
        #pragma unroll 8
        for (int i = 0; i < 64; i++) {
            int f = wv * 64 + i;
            float  w  = W2[f * 64 + lane];                    // coalesced, L2-hot
            float4 hv = h44[f];                               // b128 broadcast
            o0 = fmaf(hv.x, w, o0); o1 = fmaf(hv.y, w, o1);
            o2 = fmaf(hv.z, w, o2); o3 = fmaf(hv.w, w, o3);
        }
        partf[wv * 256 + lane]       = o0;
        partf[wv * 256 + 64 + lane]  = o1;
        partf[wv * 256 + 128 + lane] = o2;
        partf[wv * 256 + 192 + lane] = o3;
    }
    __syncthreads();
    {
        float o = partf[wv * 64 + lane]       + partf[256 + wv * 64 + lane]
                + partf[512 + wv * 64 + lane] + partf[768 + wv * 64 + lane];
        out[b * 256 + tid] = o + b2[lane];
    }
}

extern "C" void kernel_launch(void* const* d_in, const int* in_sizes, int n_in,
                              void* d_out, int out_size, void* d_ws, size_t ws_size,
                              hipStream_t stream) {
    const int*   his = (const int*)  d_in[0];
    const float* E   = (const float*)d_in[1];
    const float* S   = (const float*)d_in[2];
    const float* B0  = (const float*)d_in[3];
    const float* W1  = (const float*)d_in[4];
    const float* b1  = (const float*)d_in[5];
    const float* W2  = (const float*)d_in[6];
    const float* b2  = (const float*)d_in[7];
    float* out = (float*)d_out;
    float* P   = (float*)d_ws;                 // NVOC*64 floats = 25.6 MB scratch

    precompute_P<<<(NVOC + 255) / 256, 256, 0, stream>>>(E, S, P);
    mind_row<<<4096, 256, 0, stream>>>(his, P, B0, W1, b1, W2, b2, out);
}